// Round 5
// baseline (237.321 us; speedup 1.0000x reference)
//
#include <hip/hip_runtime.h>
#include <hip/hip_bf16.h>
#include <stdint.h>

#define M_DIM 2048
#define N_DIM 4096
#define K_DIM 4096
#define NGROUP 32
#define GSIZE 128

// GEMM tiling: 128x128 block, 4 waves (2x2), each wave 64x64 via 4x4 of
// 16x16x64 i8 MFMA. BKB = 256 codes = 2 quant groups per stage, 16 stages.
#define BM 128
#define BN 128
#define BKB 256        // bytes per LDS row = 16 chunks of 16 B

typedef __attribute__((ext_vector_type(4))) int   int32x4_t;
typedef __attribute__((ext_vector_type(4))) float f32x4_t;

// global -> LDS direct DMA, 16 B per lane. LDS dst is wave-uniform base +
// lane*16 (m104/m108); data placement chosen via per-lane global address.
static __device__ __forceinline__ void gl2lds16(const void* g, void* l) {
    auto gp = (const __attribute__((address_space(1))) unsigned int*)(uintptr_t)g;
    auto lp = (__attribute__((address_space(3))) unsigned int*)(uintptr_t)l;
    __builtin_amdgcn_global_load_lds(gp, lp, 16, 0, 0);
}

// ---------------------------------------------------------------------------
// Fused prep (R3-proven structure):
//   [0, 2048): per-token activation quant -> A8 = (q-128) int8, xscale, czp
//   [2048, +8192): weight dequant -> Bt8 = (code-wzp) int8, plus
//        WS[n] += ws[n][g] * groupsum(code-wzp) via atomics
//   [.., +512): wscales transpose -> wsct[g][n] (L2-hot table for gemm)
// ---------------------------------------------------------------------------
#define QUANT_BLOCKS M_DIM
#define DEQ_BLOCKS ((N_DIM * K_DIM) / 8 / 256)       // 8 codes / thread
#define WT_BLOCKS ((N_DIM * NGROUP) / 256)           // 1 elem / thread

__global__ __launch_bounds__(256) void prep_kernel(
        const float* __restrict__ x,
        const int* __restrict__ qw,          // [N][K] codes 0..15 as int32
        const float* __restrict__ wsc,       // [N][32]
        const int* __restrict__ wzp,         // [N][32]
        char* __restrict__ A8,               // [M][K] int8 (q-128)
        char* __restrict__ Bt8,              // [N][K] int8 (code-wzp)
        float* __restrict__ xscale,          // [M]
        float* __restrict__ xzpc,            // [M]  = 128 - zp
        float* __restrict__ WS,              // [N]  (pre-zeroed; atomics)
        float* __restrict__ wsct)            // [32][N] transposed scales
{
    const int t = threadIdx.x;
    if (blockIdx.x < QUANT_BLOCKS) {
        const int s = blockIdx.x;
        const float* xrow = x + (size_t)s * K_DIM;

        float xv[16];
        float vmin = 1e38f, vmax = -1e38f;
#pragma unroll
        for (int p = 0; p < 4; ++p) {
            float4 v = *((const float4*)(xrow + p * 1024) + t);
            xv[p*4+0] = v.x; xv[p*4+1] = v.y; xv[p*4+2] = v.z; xv[p*4+3] = v.w;
            vmin = fminf(vmin, fminf(fminf(v.x, v.y), fminf(v.z, v.w)));
            vmax = fmaxf(vmax, fmaxf(fmaxf(v.x, v.y), fmaxf(v.z, v.w)));
        }
#pragma unroll
        for (int off = 32; off > 0; off >>= 1) {
            vmin = fminf(vmin, __shfl_xor(vmin, off));
            vmax = fmaxf(vmax, __shfl_xor(vmax, off));
        }
        __shared__ float smin[4], smax[4];
        const int wave = t >> 6;
        if ((t & 63) == 0) { smin[wave] = vmin; smax[wave] = vmax; }
        __syncthreads();
        vmin = fminf(fminf(smin[0], smin[1]), fminf(smin[2], smin[3]));
        vmax = fmaxf(fmaxf(smax[0], smax[1]), fmaxf(smax[2], smax[3]));

        float sc = (vmax - vmin) / 255.0f;
        sc = fmaxf(sc, 1e-5f);
        float zp = rintf(-vmin / sc);
        zp = fminf(fmaxf(zp, 0.0f), 255.0f);

#pragma unroll
        for (int p = 0; p < 4; ++p) {
            int b[4];
#pragma unroll
            for (int e = 0; e < 4; ++e) {
                float q = fminf(fmaxf(rintf(xv[p*4+e] / sc) + zp, 0.0f), 255.0f);
                b[e] = (int)q - 128;
            }
            unsigned pack = (b[0] & 0xff) | ((b[1] & 0xff) << 8) |
                            ((b[2] & 0xff) << 16) | ((b[3] & 0xff) << 24);
            *(unsigned*)(A8 + (size_t)s * K_DIM + p * 1024 + t * 4) = pack;
        }
        if (t == 0) { xscale[s] = sc; xzpc[s] = 128.0f - zp; }
    } else if (blockIdx.x < QUANT_BLOCKS + DEQ_BLOCKS) {
        // ---- weight dequant: 8 codes/thread; 16-lane cluster = 1 group ----
        const size_t base = ((size_t)(blockIdx.x - QUANT_BLOCKS) * 256 + t) * 8;
        const int n = (int)(base >> 12);          // /4096
        const int g = (int)((base >> 7) & 31);
        const int zp = wzp[n * NGROUP + g];

        int4 c0 = *(const int4*)(qw + base);
        int4 c1 = *(const int4*)(qw + base + 4);
        int v0 = c0.x - zp, v1 = c0.y - zp, v2 = c0.z - zp, v3 = c0.w - zp;
        int v4 = c1.x - zp, v5 = c1.y - zp, v6 = c1.z - zp, v7 = c1.w - zp;
        uint2 pk;
        pk.x = (v0 & 0xff) | ((v1 & 0xff) << 8) | ((v2 & 0xff) << 16) | ((v3 & 0xff) << 24);
        pk.y = (v4 & 0xff) | ((v5 & 0xff) << 8) | ((v6 & 0xff) << 16) | ((v7 & 0xff) << 24);
        *(uint2*)(Bt8 + base) = pk;

        int s8 = v0 + v1 + v2 + v3 + v4 + v5 + v6 + v7;
#pragma unroll
        for (int off = 1; off < 16; off <<= 1) s8 += __shfl_xor(s8, off);
        if ((t & 15) == 0)
            atomicAdd(WS + n, wsc[n * NGROUP + g] * (float)s8);
    } else {
        // ---- wscales transpose ----
        const int idx = (blockIdx.x - QUANT_BLOCKS - DEQ_BLOCKS) * 256 + t;
        const int n = idx >> 5, g = idx & 31;
        wsct[g * N_DIM + n] = wsc[idx];
    }
}

// ---------------------------------------------------------------------------
// i8 grouped GEMM, 16x16x64 MFMA, 64x64 wave tile. Per group g:
//   iacc += A8 x Bt8 (exact i32), facc += wsct[g][n] * (float)iacc.
// Epilogue: out[m][n] = xscale[m] * (facc + czp[m]*WS[n]) + bias[n]
// LDS: row-major [rows][256 B], 16B chunk c of row r stored at slot c^(r&7).
// Fragment reads use the R3-measured conflict-free geometry: per quad,
// 16 consecutive rows x one chunk column family (kc = ks*4 + lquad).
// ---------------------------------------------------------------------------
__global__ __launch_bounds__(256, 2) void gemm_kernel(
        const char* __restrict__ A8,     // [M][K] int8
        const char* __restrict__ Bt8,    // [N][K] int8
        const float* __restrict__ xscale,
        const float* __restrict__ xzpc,
        const float* __restrict__ wsct,  // [32][N]
        const float* __restrict__ WS,    // [N]
        const float* __restrict__ bias,  // [N]
        float* __restrict__ out)         // [M][N] f32
{
    __shared__ __align__(16) char As[BM * BKB];   // 32 KiB
    __shared__ __align__(16) char Bs[BN * BKB];   // 32 KiB

    const int tid  = threadIdx.x;
    const int bm   = blockIdx.y;
    const int bn   = blockIdx.x;
    const int wave = tid >> 6;
    const int lane = tid & 63;
    const int wr   = (wave >> 1) * 64;   // wave row offset in 128
    const int wc   = (wave & 1) * 64;    // wave col offset in 128
    const int lrow  = lane & 15;
    const int lquad = lane >> 4;         // 0..3
    const int l7    = lrow & 7;

    const int srow4 = lane >> 4;          // row within 4-row DMA slab

    int32x4_t iacc[4][4];
    f32x4_t   facc[4][4];
    const int32x4_t zi = {0, 0, 0, 0};
#pragma unroll
    for (int i = 0; i < 4; ++i)
#pragma unroll
        for (int j = 0; j < 4; ++j) {
            iacc[i][j] = zi;
            facc[i][j] = (f32x4_t){0.f, 0.f, 0.f, 0.f};
        }

    const char* Ab = A8  + (size_t)(bm * BM) * K_DIM;
    const char* Bb = Bt8 + (size_t)(bn * BN) * K_DIM;
    const int n0 = bn * BN;

    for (int kt = 0; kt < K_DIM / BKB; ++kt) {   // 16 stages, 2 groups each
        const int k0 = kt * BKB;
        const int g0 = kt * 2;

        // prefetch both groups' scales for this wave's 4 column tiles
        float scl0[4], scl1[4];
#pragma unroll
        for (int j = 0; j < 4; ++j) {
            const int n = n0 + wc + j * 16 + lrow;
            scl0[j] = wsct[g0 * N_DIM + n];
            scl1[j] = wsct[(g0 + 1) * N_DIM + n];
        }

        __syncthreads();
        // A: 32 slabs of 4 rows x 16 chunks; wave handles 8. Same for B.
#pragma unroll
        for (int p = 0; p < 8; ++p) {
            const int rbase = (p * 4 + wave) * 4;          // wave-uniform
            const int r = rbase + srow4;
            const int cdat = (lane & 15) ^ (r & 7);
            gl2lds16(Ab + (size_t)r * K_DIM + k0 + cdat * 16, As + rbase * BKB);
            gl2lds16(Bb + (size_t)r * K_DIM + k0 + cdat * 16, Bs + rbase * BKB);
        }
        __syncthreads();

#pragma unroll
        for (int ks = 0; ks < 4; ++ks) {
            const int kc = ks * 4 + lquad;          // wanted 16B chunk
            int32x4_t af[4], bf[4];
#pragma unroll
            for (int i = 0; i < 4; ++i)
                af[i] = *(const int32x4_t*)(As + (wr + i * 16 + lrow) * BKB + ((kc ^ l7) * 16));
#pragma unroll
            for (int j = 0; j < 4; ++j)
                bf[j] = *(const int32x4_t*)(Bs + (wc + j * 16 + lrow) * BKB + ((kc ^ l7) * 16));
            const bool first = (ks & 1) == 0;       // ks 0,2 start a group
#pragma unroll
            for (int i = 0; i < 4; ++i)
#pragma unroll
                for (int j = 0; j < 4; ++j)
                    iacc[i][j] = __builtin_amdgcn_mfma_i32_16x16x64_i8(
                        af[i], bf[j], first ? zi : iacc[i][j], 0, 0, 0);

            if (ks & 1) {                           // group complete: fold
                const float* scl = (ks == 1) ? scl0 : scl1;
#pragma unroll
                for (int j = 0; j < 4; ++j)
#pragma unroll
                    for (int i = 0; i < 4; ++i)
#pragma unroll
                        for (int r = 0; r < 4; ++r)
                            facc[i][j][r] += scl[j] * (float)iacc[i][j][r];
            }
        }
    }

    // Epilogue: C/D layout col=lane&15, row=lquad*4+reg (dtype-independent)
    const int m0 = bm * BM + wr;
    float wsn[4], bb[4];
#pragma unroll
    for (int j = 0; j < 4; ++j) {
        const int n = n0 + wc + j * 16 + lrow;
        wsn[j] = WS[n]; bb[j] = bias[n];
    }
#pragma unroll
    for (int i = 0; i < 4; ++i) {
#pragma unroll
        for (int r = 0; r < 4; ++r) {
            const int m = m0 + i * 16 + lquad * 4 + r;
            const float xs  = xscale[m];
            const float czp = xzpc[m];
#pragma unroll
            for (int j = 0; j < 4; ++j) {
                const int n = n0 + wc + j * 16 + lrow;
                out[(size_t)m * N_DIM + n] = xs * (facc[i][j][r] + czp * wsn[j]) + bb[j];
            }
        }
    }
}

extern "C" void kernel_launch(void* const* d_in, const int* in_sizes, int n_in,
                              void* d_out, int out_size, void* d_ws, size_t ws_size,
                              hipStream_t stream) {
    const float* x     = (const float*)d_in[0];
    const int*   qw    = (const int*)d_in[1];
    const float* wsc   = (const float*)d_in[2];
    const int*   wzp   = (const int*)d_in[3];
    const float* bias  = (const float*)d_in[4];
    float* out = (float*)d_out;

    // workspace layout
    char* A8  = (char*)d_ws;                                   //  8 MiB
    char* Bt8 = A8 + (size_t)M_DIM * K_DIM;                    // 16 MiB
    float* xscale = (float*)(Bt8 + (size_t)N_DIM * K_DIM);     //  8 KiB
    float* xzpc   = xscale + M_DIM;                            //  8 KiB
    float* WS     = xzpc + M_DIM;                              // 16 KiB
    float* wsct   = WS + N_DIM;                                // 512 KiB

    hipMemsetAsync(WS, 0, N_DIM * sizeof(float), stream);
    prep_kernel<<<QUANT_BLOCKS + DEQ_BLOCKS + WT_BLOCKS, 256, 0, stream>>>(
        x, qw, wsc, wzp, A8, Bt8, xscale, xzpc, WS, wsct);
    dim3 grid(N_DIM / BN, M_DIM / BM);
    gemm_kernel<<<grid, 256, 0, stream>>>(A8, Bt8, xscale, xzpc, wsct, WS, bias, out);
}

// Round 6
// 182.089 us; speedup vs baseline: 1.3033x; 1.3033x over previous
//
#include <hip/hip_runtime.h>
#include <hip/hip_bf16.h>
#include <stdint.h>

#define M_DIM 2048
#define N_DIM 4096
#define K_DIM 4096
#define NGROUP 32
#define GSIZE 128

// GEMM tiling (R3-proven geometry): 128x64 block, 4 waves each 64x32 via
// 4x2 of 16x16x64 i8 MFMA. BKB = 128 bytes = 1 quant group per stage.
// LDS rows 128 B = 8 chunks of 16 B; chunk c of row r at slot c^(r&7)
// [measured R3: 0 bank conflicts; BKB=256 variants measured 4.2M - avoid].
#define BM 128
#define BN 64
#define BKB 128

typedef __attribute__((ext_vector_type(4))) int   int32x4_t;
typedef __attribute__((ext_vector_type(4))) float f32x4_t;

// global -> LDS direct DMA, 16 B per lane. LDS dst is wave-uniform base +
// lane*16 (m104/m108); data placement chosen via per-lane global address.
static __device__ __forceinline__ void gl2lds16(const void* g, void* l) {
    auto gp = (const __attribute__((address_space(1))) unsigned int*)(uintptr_t)g;
    auto lp = (__attribute__((address_space(3))) unsigned int*)(uintptr_t)l;
    __builtin_amdgcn_global_load_lds(gp, lp, 16, 0, 0);
}

// ---------------------------------------------------------------------------
// Fused prep:
//   [0, 2048): per-token activation quant -> A8 = (q-128) int8, xscale, czp
//   [2048, +8192): weight dequant -> Bt8 = (code-wzp) int8, plus coalesced
//        per-(n,g) integer group sums Sw (NO atomics)
//   [.., +512): wscales transpose -> wsct[g][n] (L2-hot table for gemm)
// ---------------------------------------------------------------------------
#define QUANT_BLOCKS M_DIM
#define DEQ_BLOCKS ((N_DIM * K_DIM) / 8 / 256)       // 8 codes / thread
#define WT_BLOCKS ((N_DIM * NGROUP) / 256)           // 1 elem / thread

__global__ __launch_bounds__(256) void prep_kernel(
        const float* __restrict__ x,
        const int* __restrict__ qw,          // [N][K] codes 0..15 as int32
        const float* __restrict__ wsc,       // [N][32]
        const int* __restrict__ wzp,         // [N][32]
        char* __restrict__ A8,               // [M][K] int8 (q-128)
        char* __restrict__ Bt8,              // [N][K] int8 (code-wzp)
        float* __restrict__ xscale,          // [M]
        float* __restrict__ xzpc,            // [M]  = 128 - zp
        int* __restrict__ Sw,                // [N][32] group sums
        float* __restrict__ wsct)            // [32][N] transposed scales
{
    const int t = threadIdx.x;
    if (blockIdx.x < QUANT_BLOCKS) {
        const int s = blockIdx.x;
        const float* xrow = x + (size_t)s * K_DIM;

        float xv[16];
        float vmin = 1e38f, vmax = -1e38f;
#pragma unroll
        for (int p = 0; p < 4; ++p) {
            float4 v = *((const float4*)(xrow + p * 1024) + t);
            xv[p*4+0] = v.x; xv[p*4+1] = v.y; xv[p*4+2] = v.z; xv[p*4+3] = v.w;
            vmin = fminf(vmin, fminf(fminf(v.x, v.y), fminf(v.z, v.w)));
            vmax = fmaxf(vmax, fmaxf(fmaxf(v.x, v.y), fmaxf(v.z, v.w)));
        }
#pragma unroll
        for (int off = 32; off > 0; off >>= 1) {
            vmin = fminf(vmin, __shfl_xor(vmin, off));
            vmax = fmaxf(vmax, __shfl_xor(vmax, off));
        }
        __shared__ float smin[4], smax[4];
        const int wave = t >> 6;
        if ((t & 63) == 0) { smin[wave] = vmin; smax[wave] = vmax; }
        __syncthreads();
        vmin = fminf(fminf(smin[0], smin[1]), fminf(smin[2], smin[3]));
        vmax = fmaxf(fmaxf(smax[0], smax[1]), fmaxf(smax[2], smax[3]));

        float sc = (vmax - vmin) / 255.0f;
        sc = fmaxf(sc, 1e-5f);
        float zp = rintf(-vmin / sc);
        zp = fminf(fmaxf(zp, 0.0f), 255.0f);

#pragma unroll
        for (int p = 0; p < 4; ++p) {
            int b[4];
#pragma unroll
            for (int e = 0; e < 4; ++e) {
                float q = fminf(fmaxf(rintf(xv[p*4+e] / sc) + zp, 0.0f), 255.0f);
                b[e] = (int)q - 128;
            }
            unsigned pack = (b[0] & 0xff) | ((b[1] & 0xff) << 8) |
                            ((b[2] & 0xff) << 16) | ((b[3] & 0xff) << 24);
            *(unsigned*)(A8 + (size_t)s * K_DIM + p * 1024 + t * 4) = pack;
        }
        if (t == 0) { xscale[s] = sc; xzpc[s] = 128.0f - zp; }
    } else if (blockIdx.x < QUANT_BLOCKS + DEQ_BLOCKS) {
        // ---- weight dequant: 8 codes/thread; 16-lane cluster = 1 group ----
        const size_t base = ((size_t)(blockIdx.x - QUANT_BLOCKS) * 256 + t) * 8;
        const int n = (int)(base >> 12);          // /4096
        const int g = (int)((base >> 7) & 31);
        const int zp = wzp[n * NGROUP + g];

        int4 c0 = *(const int4*)(qw + base);
        int4 c1 = *(const int4*)(qw + base + 4);
        int v0 = c0.x - zp, v1 = c0.y - zp, v2 = c0.z - zp, v3 = c0.w - zp;
        int v4 = c1.x - zp, v5 = c1.y - zp, v6 = c1.z - zp, v7 = c1.w - zp;
        uint2 pk;
        pk.x = (v0 & 0xff) | ((v1 & 0xff) << 8) | ((v2 & 0xff) << 16) | ((v3 & 0xff) << 24);
        pk.y = (v4 & 0xff) | ((v5 & 0xff) << 8) | ((v6 & 0xff) << 16) | ((v7 & 0xff) << 24);
        *(uint2*)(Bt8 + base) = pk;

        int s8 = v0 + v1 + v2 + v3 + v4 + v5 + v6 + v7;
#pragma unroll
        for (int off = 1; off < 16; off <<= 1) s8 += __shfl_xor(s8, off);
        if ((t & 15) == 0)
            Sw[n * NGROUP + g] = s8;     // coalesced, no atomic
    } else {
        // ---- wscales transpose ----
        const int idx = (blockIdx.x - QUANT_BLOCKS - DEQ_BLOCKS) * 256 + t;
        const int n = idx >> 5, g = idx & 31;
        wsct[g * N_DIM + n] = wsc[idx];
    }
}

// tiny: WS[n] = sum_g wsc[n][g] * Sw[n][g]
__global__ __launch_bounds__(256) void ws_kernel(
        const float* __restrict__ wsc, const int* __restrict__ Sw,
        float* __restrict__ WS)
{
    const int n = blockIdx.x * 256 + threadIdx.x;
    const float4* w4 = (const float4*)(wsc + n * NGROUP);
    const int4*   s4 = (const int4*)(Sw + n * NGROUP);
    float acc = 0.f;
#pragma unroll
    for (int p = 0; p < 8; ++p) {
        float4 w = w4[p]; int4 s = s4[p];
        acc += w.x * (float)s.x + w.y * (float)s.y +
               w.z * (float)s.z + w.w * (float)s.w;
    }
    WS[n] = acc;
}

// ---------------------------------------------------------------------------
// i8 grouped GEMM (R3 geometry + double-buffered DMA staging).
// Per stage kt (= group g): iacc = A8 x Bt8 (exact i32, 2 k-steps),
// facc += wsct[g][n] * (float)iacc. Epilogue:
//   out[m][n] = xscale[m] * (facc + czp[m]*WS[n]) + bias[n]
// ---------------------------------------------------------------------------
__global__ __launch_bounds__(256, 3) void gemm_kernel(
        const char* __restrict__ A8,     // [M][K] int8
        const char* __restrict__ Bt8,    // [N][K] int8
        const float* __restrict__ xscale,
        const float* __restrict__ xzpc,
        const float* __restrict__ wsct,  // [32][N]
        const float* __restrict__ WS,    // [N]
        const float* __restrict__ bias,  // [N]
        float* __restrict__ out)         // [M][N] f32
{
    __shared__ __align__(16) char As[2][BM * BKB];   // 2 x 16 KiB
    __shared__ __align__(16) char Bs[2][BN * BKB];   // 2 x  8 KiB

    const int tid  = threadIdx.x;
    const int bm   = blockIdx.y;
    const int bn   = blockIdx.x;
    const int wave = tid >> 6;
    const int lane = tid & 63;
    const int wr   = (wave >> 1) * 64;   // wave row offset in 128
    const int wc   = (wave & 1) * 32;    // wave col offset in 64
    const int lrow  = lane & 15;
    const int lquad = lane >> 4;         // 0..3
    const int l7    = lrow & 7;

    const int srow8 = lane >> 3;          // row within 8-row DMA slab
    const int cdat  = (lane & 7) ^ srow8; // source 16B chunk for this slot

    int32x4_t iacc[4][2];
    f32x4_t   facc[4][2];
    const int32x4_t zi = {0, 0, 0, 0};
#pragma unroll
    for (int i = 0; i < 4; ++i)
#pragma unroll
        for (int j = 0; j < 2; ++j) {
            iacc[i][j] = zi;
            facc[i][j] = (f32x4_t){0.f, 0.f, 0.f, 0.f};
        }

    const char* Ab = A8  + (size_t)(bm * BM) * K_DIM;
    const char* Bb = Bt8 + (size_t)(bn * BN) * K_DIM;
    const int n0 = bn * BN;
    const int ncol0 = n0 + wc + 0  + lrow;   // this lane's two output columns
    const int ncol1 = n0 + wc + 16 + lrow;

    // ---- preload stage 0 into buffer 0 ----
#pragma unroll
    for (int p = 0; p < 4; ++p) {
        const int rbase = (p * 4 + wave) * 8;            // wave-uniform
        gl2lds16(Ab + (size_t)(rbase + srow8) * K_DIM + cdat * 16,
                 As[0] + rbase * BKB);
    }
#pragma unroll
    for (int p = 0; p < 2; ++p) {
        const int rbase = (p * 4 + wave) * 8;
        gl2lds16(Bb + (size_t)(rbase + srow8) * K_DIM + cdat * 16,
                 Bs[0] + rbase * BKB);
    }
    float scl0 = wsct[ncol0];             // group 0 scales
    float scl1 = wsct[ncol1];

    for (int kt = 0; kt < K_DIM / GSIZE; ++kt) {   // 32 stages, 1 group each
        const int cur = kt & 1;
        __syncthreads();   // publishes buf[cur] (per-wave vmcnt drained first)

        // issue next stage's DMA into the other buffer (overlaps compute)
        if (kt < 31) {
            const int k0 = (kt + 1) * GSIZE;
#pragma unroll
            for (int p = 0; p < 4; ++p) {
                const int rbase = (p * 4 + wave) * 8;
                gl2lds16(Ab + (size_t)(rbase + srow8) * K_DIM + k0 + cdat * 16,
                         As[cur ^ 1] + rbase * BKB);
            }
#pragma unroll
            for (int p = 0; p < 2; ++p) {
                const int rbase = (p * 4 + wave) * 8;
                gl2lds16(Bb + (size_t)(rbase + srow8) * K_DIM + k0 + cdat * 16,
                         Bs[cur ^ 1] + rbase * BKB);
            }
        }
        // prefetch next group's scales
        float nscl0 = 0.f, nscl1 = 0.f;
        if (kt < 31) {
            nscl0 = wsct[(kt + 1) * N_DIM + ncol0];
            nscl1 = wsct[(kt + 1) * N_DIM + ncol1];
        }

        // compute current stage from buf[cur]
#pragma unroll
        for (int ks = 0; ks < 2; ++ks) {
            const int kc = ks * 4 + lquad;          // wanted 16B chunk
            int32x4_t af[4], bf[2];
#pragma unroll
            for (int i = 0; i < 4; ++i)
                af[i] = *(const int32x4_t*)(As[cur] + (wr + i * 16 + lrow) * BKB + ((kc ^ l7) * 16));
#pragma unroll
            for (int j = 0; j < 2; ++j)
                bf[j] = *(const int32x4_t*)(Bs[cur] + (wc + j * 16 + lrow) * BKB + ((kc ^ l7) * 16));
#pragma unroll
            for (int i = 0; i < 4; ++i)
#pragma unroll
                for (int j = 0; j < 2; ++j)
                    iacc[i][j] = __builtin_amdgcn_mfma_i32_16x16x64_i8(
                        af[i], bf[j], ks == 0 ? zi : iacc[i][j], 0, 0, 0);
        }

        // fold this group's integer acc with its weight scale
#pragma unroll
        for (int i = 0; i < 4; ++i) {
#pragma unroll
            for (int r = 0; r < 4; ++r) {
                facc[i][0][r] += scl0 * (float)iacc[i][0][r];
                facc[i][1][r] += scl1 * (float)iacc[i][1][r];
            }
        }
        scl0 = nscl0; scl1 = nscl1;
    }

    // Epilogue: C/D layout col=lane&15, row=lquad*4+reg (dtype-independent)
    const int m0 = bm * BM + wr;
    const float wsn0 = WS[ncol0], bb0 = bias[ncol0];
    const float wsn1 = WS[ncol1], bb1 = bias[ncol1];
#pragma unroll
    for (int i = 0; i < 4; ++i) {
#pragma unroll
        for (int r = 0; r < 4; ++r) {
            const int m = m0 + i * 16 + lquad * 4 + r;
            const float xs  = xscale[m];
            const float czp = xzpc[m];
            out[(size_t)m * N_DIM + ncol0] = xs * (facc[i][0][r] + czp * wsn0) + bb0;
            out[(size_t)m * N_DIM + ncol1] = xs * (facc[i][1][r] + czp * wsn1) + bb1;
        }
    }
}

extern "C" void kernel_launch(void* const* d_in, const int* in_sizes, int n_in,
                              void* d_out, int out_size, void* d_ws, size_t ws_size,
                              hipStream_t stream) {
    const float* x     = (const float*)d_in[0];
    const int*   qw    = (const int*)d_in[1];
    const float* wsc   = (const float*)d_in[2];
    const int*   wzp   = (const int*)d_in[3];
    const float* bias  = (const float*)d_in[4];
    float* out = (float*)d_out;

    // workspace layout
    char* A8  = (char*)d_ws;                                   //  8 MiB
    char* Bt8 = A8 + (size_t)M_DIM * K_DIM;                    // 16 MiB
    float* xscale = (float*)(Bt8 + (size_t)N_DIM * K_DIM);     //  8 KiB
    float* xzpc   = xscale + M_DIM;                            //  8 KiB
    float* WS     = xzpc + M_DIM;                              // 16 KiB
    int*   Sw     = (int*)(WS + N_DIM);                        // 512 KiB
    float* wsct   = (float*)(Sw + N_DIM * NGROUP);             // 512 KiB

    prep_kernel<<<QUANT_BLOCKS + DEQ_BLOCKS + WT_BLOCKS, 256, 0, stream>>>(
        x, qw, wsc, wzp, A8, Bt8, xscale, xzpc, Sw, wsct);
    ws_kernel<<<N_DIM / 256, 256, 0, stream>>>(wsc, Sw, WS);
    dim3 grid(N_DIM / BN, M_DIM / BM);
    gemm_kernel<<<grid, 256, 0, stream>>>(A8, Bt8, xscale, xzpc, wsct, WS, bias, out);
}

// Round 7
// 179.227 us; speedup vs baseline: 1.3241x; 1.0160x over previous
//
#include <hip/hip_runtime.h>
#include <hip/hip_bf16.h>
#include <stdint.h>

#define M_DIM 2048
#define N_DIM 4096
#define K_DIM 4096
#define NGROUP 32
#define GSIZE 128

// GEMM tiling (R3/R6-proven geometry): 128x64 block, 4 waves each 64x32 via
// 4x2 of 16x16x64 i8 MFMA. BKB = 128 bytes per stage.
// LDS rows 128 B = 8 chunks of 16 B; chunk c of row r at slot c^(r&7)
// [measured R3/R6: 0 bank conflicts; BKB=256 variants measured 4.2M - avoid].
#define BM 128
#define BN 64
#define BKB 128

#define RQ_UP   (127.0f / 15.0f)   // weight requant gain
#define RQ_DOWN (15.0f / 127.0f)

typedef __attribute__((ext_vector_type(4))) int   int32x4_t;
typedef __attribute__((ext_vector_type(4))) float f32x4_t;

// global -> LDS direct DMA, 16 B per lane. LDS dst is wave-uniform base +
// lane*16 (m104/m108); data placement chosen via per-lane global address.
static __device__ __forceinline__ void gl2lds16(const void* g, void* l) {
    auto gp = (const __attribute__((address_space(1))) unsigned int*)(uintptr_t)g;
    auto lp = (__attribute__((address_space(3))) unsigned int*)(uintptr_t)l;
    __builtin_amdgcn_global_load_lds(gp, lp, 16, 0, 0);
}

// ---------------------------------------------------------------------------
// sn_kernel: per output channel n, s_n = max_g ws[n][g];
//   rsn[n] = (127/15)/s_n  (requant gain), fws[n] = s_n*15/127 (dequant).
// ---------------------------------------------------------------------------
__global__ __launch_bounds__(256) void sn_kernel(
        const float* __restrict__ wsc, float* __restrict__ rsn,
        float* __restrict__ fws)
{
    const int n = blockIdx.x * 256 + threadIdx.x;
    const float4* w4 = (const float4*)(wsc + (size_t)n * NGROUP);
    float s = 0.f;
#pragma unroll
    for (int p = 0; p < 8; ++p) {
        float4 w = w4[p];
        s = fmaxf(s, fmaxf(fmaxf(w.x, w.y), fmaxf(w.z, w.w)));
    }
    rsn[n] = RQ_UP / s;
    fws[n] = s * RQ_DOWN;
}

// ---------------------------------------------------------------------------
// Fused prep:
//   [0, 2048): per-token activation quant -> A8 = (q-128) int8, xscale, czp
//   [2048, ..): weight requant -> Bt8[n][k] = round((code-wzp)*ws[g]*rsn[n])
//        int8 in [-127,127], plus coalesced per-(n,g) sums Sw of Bt8.
// ---------------------------------------------------------------------------
#define QUANT_BLOCKS M_DIM
#define DEQ_BLOCKS ((N_DIM * K_DIM) / 8 / 256)       // 8 codes / thread

__global__ __launch_bounds__(256) void prep_kernel(
        const float* __restrict__ x,
        const int* __restrict__ qw,          // [N][K] codes 0..15 as int32
        const float* __restrict__ wsc,       // [N][32]
        const int* __restrict__ wzp,         // [N][32]
        const float* __restrict__ rsn,       // [N]
        char* __restrict__ A8,               // [M][K] int8 (q-128)
        char* __restrict__ Bt8,              // [N][K] int8 requantized
        float* __restrict__ xscale,          // [M]
        float* __restrict__ xzpc,            // [M]  = 128 - zp
        int* __restrict__ Sw)                // [N][32] group sums of Bt8
{
    const int t = threadIdx.x;
    if (blockIdx.x < QUANT_BLOCKS) {
        const int s = blockIdx.x;
        const float* xrow = x + (size_t)s * K_DIM;

        float xv[16];
        float vmin = 1e38f, vmax = -1e38f;
#pragma unroll
        for (int p = 0; p < 4; ++p) {
            float4 v = *((const float4*)(xrow + p * 1024) + t);
            xv[p*4+0] = v.x; xv[p*4+1] = v.y; xv[p*4+2] = v.z; xv[p*4+3] = v.w;
            vmin = fminf(vmin, fminf(fminf(v.x, v.y), fminf(v.z, v.w)));
            vmax = fmaxf(vmax, fmaxf(fmaxf(v.x, v.y), fmaxf(v.z, v.w)));
        }
#pragma unroll
        for (int off = 32; off > 0; off >>= 1) {
            vmin = fminf(vmin, __shfl_xor(vmin, off));
            vmax = fmaxf(vmax, __shfl_xor(vmax, off));
        }
        __shared__ float smin[4], smax[4];
        const int wave = t >> 6;
        if ((t & 63) == 0) { smin[wave] = vmin; smax[wave] = vmax; }
        __syncthreads();
        vmin = fminf(fminf(smin[0], smin[1]), fminf(smin[2], smin[3]));
        vmax = fmaxf(fmaxf(smax[0], smax[1]), fmaxf(smax[2], smax[3]));

        float sc = (vmax - vmin) / 255.0f;
        sc = fmaxf(sc, 1e-5f);
        float zp = rintf(-vmin / sc);
        zp = fminf(fmaxf(zp, 0.0f), 255.0f);

#pragma unroll
        for (int p = 0; p < 4; ++p) {
            int b[4];
#pragma unroll
            for (int e = 0; e < 4; ++e) {
                float q = fminf(fmaxf(rintf(xv[p*4+e] / sc) + zp, 0.0f), 255.0f);
                b[e] = (int)q - 128;
            }
            unsigned pack = (b[0] & 0xff) | ((b[1] & 0xff) << 8) |
                            ((b[2] & 0xff) << 16) | ((b[3] & 0xff) << 24);
            *(unsigned*)(A8 + (size_t)s * K_DIM + p * 1024 + t * 4) = pack;
        }
        if (t == 0) { xscale[s] = sc; xzpc[s] = 128.0f - zp; }
    } else {
        // ---- weight requant: 8 codes/thread; 16-lane cluster = 1 group ----
        const size_t base = ((size_t)(blockIdx.x - QUANT_BLOCKS) * 256 + t) * 8;
        const int n = (int)(base >> 12);          // /4096
        const int g = (int)((base >> 7) & 31);
        const int zp = wzp[n * NGROUP + g];
        const float factor = wsc[n * NGROUP + g] * rsn[n];   // <= 127/15

        int4 c0 = *(const int4*)(qw + base);
        int4 c1 = *(const int4*)(qw + base + 4);
        int w[8];
        w[0] = (int)rintf((float)(c0.x - zp) * factor);
        w[1] = (int)rintf((float)(c0.y - zp) * factor);
        w[2] = (int)rintf((float)(c0.z - zp) * factor);
        w[3] = (int)rintf((float)(c0.w - zp) * factor);
        w[4] = (int)rintf((float)(c1.x - zp) * factor);
        w[5] = (int)rintf((float)(c1.y - zp) * factor);
        w[6] = (int)rintf((float)(c1.z - zp) * factor);
        w[7] = (int)rintf((float)(c1.w - zp) * factor);
        uint2 pk;
        pk.x = (w[0] & 0xff) | ((w[1] & 0xff) << 8) | ((w[2] & 0xff) << 16) | ((w[3] & 0xff) << 24);
        pk.y = (w[4] & 0xff) | ((w[5] & 0xff) << 8) | ((w[6] & 0xff) << 16) | ((w[7] & 0xff) << 24);
        *(uint2*)(Bt8 + base) = pk;

        int s8 = w[0] + w[1] + w[2] + w[3] + w[4] + w[5] + w[6] + w[7];
#pragma unroll
        for (int off = 1; off < 16; off <<= 1) s8 += __shfl_xor(s8, off);
        if ((t & 15) == 0)
            Sw[n * NGROUP + g] = s8;     // coalesced, no atomic
    }
}

// tiny: WSf[n] = fws[n] * sum_g Sw[n][g]
__global__ __launch_bounds__(256) void ws_kernel(
        const float* __restrict__ fws, const int* __restrict__ Sw,
        float* __restrict__ WSf)
{
    const int n = blockIdx.x * 256 + threadIdx.x;
    const int4* s4 = (const int4*)(Sw + (size_t)n * NGROUP);
    int acc = 0;
#pragma unroll
    for (int p = 0; p < 8; ++p) {
        int4 s = s4[p];
        acc += s.x + s.y + s.z + s.w;
    }
    WSf[n] = fws[n] * (float)acc;
}

// ---------------------------------------------------------------------------
// Pure i8 GEMM, K=4096, iacc persistent in AGPRs (no in-loop fold).
// Epilogue: out[m][n] = xscale[m]*(fws[n]*iacc + czp[m]*WSf[n]) + bias[n]
// ---------------------------------------------------------------------------
__global__ __launch_bounds__(256, 3) void gemm_kernel(
        const char* __restrict__ A8,     // [M][K] int8
        const char* __restrict__ Bt8,    // [N][K] int8
        const float* __restrict__ xscale,
        const float* __restrict__ xzpc,
        const float* __restrict__ fws,   // [N]
        const float* __restrict__ WSf,   // [N]
        const float* __restrict__ bias,  // [N]
        float* __restrict__ out)         // [M][N] f32
{
    __shared__ __align__(16) char As[2][BM * BKB];   // 2 x 16 KiB
    __shared__ __align__(16) char Bs[2][BN * BKB];   // 2 x  8 KiB

    const int tid  = threadIdx.x;
    const int bm   = blockIdx.y;
    const int bn   = blockIdx.x;
    const int wave = tid >> 6;
    const int lane = tid & 63;
    const int wr   = (wave >> 1) * 64;   // wave row offset in 128
    const int wc   = (wave & 1) * 32;    // wave col offset in 64
    const int lrow  = lane & 15;
    const int lquad = lane >> 4;         // 0..3
    const int l7    = lrow & 7;

    const int srow8 = lane >> 3;          // row within 8-row DMA slab
    const int cdat  = (lane & 7) ^ srow8; // source 16B chunk for this slot

    int32x4_t iacc[4][2];
    const int32x4_t zi = {0, 0, 0, 0};
#pragma unroll
    for (int i = 0; i < 4; ++i)
#pragma unroll
        for (int j = 0; j < 2; ++j) iacc[i][j] = zi;

    const char* Ab = A8  + (size_t)(bm * BM) * K_DIM;
    const char* Bb = Bt8 + (size_t)(bn * BN) * K_DIM;
    const int n0 = bn * BN;
    const int ncol0 = n0 + wc + 0  + lrow;   // this lane's two output columns
    const int ncol1 = n0 + wc + 16 + lrow;

    // ---- preload stage 0 into buffer 0 ----
#pragma unroll
    for (int p = 0; p < 4; ++p) {
        const int rbase = (p * 4 + wave) * 8;            // wave-uniform
        gl2lds16(Ab + (size_t)(rbase + srow8) * K_DIM + cdat * 16,
                 As[0] + rbase * BKB);
    }
#pragma unroll
    for (int p = 0; p < 2; ++p) {
        const int rbase = (p * 4 + wave) * 8;
        gl2lds16(Bb + (size_t)(rbase + srow8) * K_DIM + cdat * 16,
                 Bs[0] + rbase * BKB);
    }

    for (int kt = 0; kt < K_DIM / GSIZE; ++kt) {   // 32 stages
        const int cur = kt & 1;
        __syncthreads();   // publishes buf[cur]

        // issue next stage's DMA into the other buffer (overlaps compute)
        if (kt < 31) {
            const int k0 = (kt + 1) * GSIZE;
#pragma unroll
            for (int p = 0; p < 4; ++p) {
                const int rbase = (p * 4 + wave) * 8;
                gl2lds16(Ab + (size_t)(rbase + srow8) * K_DIM + k0 + cdat * 16,
                         As[cur ^ 1] + rbase * BKB);
            }
#pragma unroll
            for (int p = 0; p < 2; ++p) {
                const int rbase = (p * 4 + wave) * 8;
                gl2lds16(Bb + (size_t)(rbase + srow8) * K_DIM + k0 + cdat * 16,
                         Bs[cur ^ 1] + rbase * BKB);
            }
        }

        // compute current stage from buf[cur]
#pragma unroll
        for (int ks = 0; ks < 2; ++ks) {
            const int kc = ks * 4 + lquad;          // wanted 16B chunk
            int32x4_t af[4], bf[2];
#pragma unroll
            for (int i = 0; i < 4; ++i)
                af[i] = *(const int32x4_t*)(As[cur] + (wr + i * 16 + lrow) * BKB + ((kc ^ l7) * 16));
#pragma unroll
            for (int j = 0; j < 2; ++j)
                bf[j] = *(const int32x4_t*)(Bs[cur] + (wc + j * 16 + lrow) * BKB + ((kc ^ l7) * 16));
#pragma unroll
            for (int i = 0; i < 4; ++i)
#pragma unroll
                for (int j = 0; j < 2; ++j)
                    iacc[i][j] = __builtin_amdgcn_mfma_i32_16x16x64_i8(
                        af[i], bf[j], iacc[i][j], 0, 0, 0);
        }
    }

    // Epilogue: C/D layout col=lane&15, row=lquad*4+reg (dtype-independent)
    const int m0 = bm * BM + wr;
    const float fn0 = fws[ncol0], wf0 = WSf[ncol0], bb0 = bias[ncol0];
    const float fn1 = fws[ncol1], wf1 = WSf[ncol1], bb1 = bias[ncol1];
#pragma unroll
    for (int i = 0; i < 4; ++i) {
#pragma unroll
        for (int r = 0; r < 4; ++r) {
            const int m = m0 + i * 16 + lquad * 4 + r;
            const float xs  = xscale[m];
            const float czp = xzpc[m];
            out[(size_t)m * N_DIM + ncol0] =
                xs * (fn0 * (float)iacc[i][0][r] + czp * wf0) + bb0;
            out[(size_t)m * N_DIM + ncol1] =
                xs * (fn1 * (float)iacc[i][1][r] + czp * wf1) + bb1;
        }
    }
}

extern "C" void kernel_launch(void* const* d_in, const int* in_sizes, int n_in,
                              void* d_out, int out_size, void* d_ws, size_t ws_size,
                              hipStream_t stream) {
    const float* x     = (const float*)d_in[0];
    const int*   qw    = (const int*)d_in[1];
    const float* wsc   = (const float*)d_in[2];
    const int*   wzp   = (const int*)d_in[3];
    const float* bias  = (const float*)d_in[4];
    float* out = (float*)d_out;

    // workspace layout
    char* A8  = (char*)d_ws;                                   //  8 MiB
    char* Bt8 = A8 + (size_t)M_DIM * K_DIM;                    // 16 MiB
    float* xscale = (float*)(Bt8 + (size_t)N_DIM * K_DIM);     //  8 KiB
    float* xzpc   = xscale + M_DIM;                            //  8 KiB
    int*   Sw     = (int*)(xzpc + M_DIM);                      // 512 KiB
    float* rsn    = (float*)(Sw + (size_t)N_DIM * NGROUP);     // 16 KiB
    float* fws    = rsn + N_DIM;                               // 16 KiB
    float* WSf    = fws + N_DIM;                               // 16 KiB

    sn_kernel<<<N_DIM / 256, 256, 0, stream>>>(wsc, rsn, fws);
    prep_kernel<<<QUANT_BLOCKS + DEQ_BLOCKS, 256, 0, stream>>>(
        x, qw, wsc, wzp, rsn, A8, Bt8, xscale, xzpc, Sw);
    ws_kernel<<<N_DIM / 256, 256, 0, stream>>>(fws, Sw, WSf);
    dim3 grid(N_DIM / BN, M_DIM / BM);
    gemm_kernel<<<grid, 256, 0, stream>>>(A8, Bt8, xscale, xzpc, fws, WSf, bias, out);
}